// Round 2
// baseline (400.072 us; speedup 1.0000x reference)
//
#include <hip/hip_runtime.h>
#include <math.h>

#define HH 512
#define WW 512
#define PP (HH * WW)          // 262144 pixels
#define GG 64                 // gt points per batch
#define BB 4                  // batches
#define BLOCKS_X 128
#define THREADS 256
#define KPIX 8                // pixels per thread = PP / (BLOCKS_X*THREADS)
#define CHUNK 4
#define MAX_DIST 724.0773439350246f   // sqrt(512^2 + 512^2)
#define EPSV 1e-6f

// Workspace layout (floats):
//   ws[0..3]    t1_sum[b]
//   ws[4..7]    n_est[b]
//   ws[8..263]  gmin bits, uint, [b][g]  (non-negative floats -> uint order-preserving)

__global__ void ghd_init(float* __restrict__ ws) {
    int t = threadIdx.x;
    if (t < 8) ws[t] = 0.0f;
    unsigned* gm = reinterpret_cast<unsigned*>(ws) + 8;
    if (t < BB * GG) gm[t] = 0x7f7fffffu;  // FLT_MAX bits
}

__launch_bounds__(256, 2)
__global__ void ghd_main(const float* __restrict__ prob_map,
                         const float* __restrict__ prob_y,
                         const float* __restrict__ gt,
                         const int*   __restrict__ osz,
                         float*       __restrict__ ws) {
    const int b    = blockIdx.y;
    const int tid  = threadIdx.x;
    const int lane = tid & 63;

    __shared__ float4   gdat[GG];      // (ny0, ny1, py, py^2)
    __shared__ unsigned sgmin[GG];     // per-block per-g min (uint bits)
    __shared__ float    s_t1, s_ne;

    const float nf0 = (float)osz[b * 2 + 0] * (1.0f / HH);
    const float nf1 = (float)osz[b * 2 + 1] * (1.0f / WW);

    if (tid < GG) {
        float g0 = gt[(b * GG + tid) * 2 + 0];
        float g1 = gt[(b * GG + tid) * 2 + 1];
        float py = prob_y[b * GG + tid];
        gdat[tid]  = make_float4(nf0 * g0, nf1 * g1, py, py * py);
        sgmin[tid] = 0x7f7fffffu;
    }
    if (tid == 0) { s_t1 = 0.0f; s_ne = 0.0f; }
    __syncthreads();

    float ming[GG];
#pragma unroll
    for (int g = 0; g < GG; ++g) ming[g] = 3.4e38f;

    float t1 = 0.0f, ne = 0.0f;
    const float* __restrict__ pm = prob_map + (size_t)b * PP;

#pragma unroll
    for (int c = 0; c < KPIX / CHUNK; ++c) {
        float p[CHUNK], nx0[CHUNK], nx1[CHUNK], base[CHUNK], m1q[CHUNK];
#pragma unroll
        for (int k = 0; k < CHUNK; ++k) {
            int pid = blockIdx.x * THREADS + tid + (c * CHUNK + k) * (BLOCKS_X * THREADS);
            p[k]    = pm[pid];
            nx0[k]  = nf0 * (float)(pid >> 9);          // pid / W
            nx1[k]  = nf1 * (float)(pid & (WW - 1));    // pid % W
            base[k] = (1.0f - p[k]) * MAX_DIST;
            m1q[k]  = 3.4e38f;
            ne     += p[k];
        }
#pragma unroll
        for (int g = 0; g < GG; ++g) {
            float4 gd = gdat[g];
            float  mg = ming[g];
#pragma unroll
            for (int k = 0; k < CHUNK; ++k) {
                float dx = nx0[k] - gd.x;
                float dy = nx1[k] - gd.y;
                float d2 = fmaf(dx, dx, dy * dy);
                m1q[k]   = fminf(m1q[k], gd.w * d2);                 // min_g (py^2 d^2)
                float d  = __builtin_amdgcn_sqrtf(d2);
                mg       = fminf(mg, fmaf(p[k], gd.z * d, base[k])); // (1-p)MAX + p*py*d
            }
            ming[g] = mg;
        }
#pragma unroll
        for (int k = 0; k < CHUNK; ++k)
            t1 = fmaf(p[k], __builtin_amdgcn_sqrtf(m1q[k]), t1);
    }

    // ---- block reductions ----
    // per-g min: one LDS atomicMin per g per thread (uint order == float order, all >= 0)
#pragma unroll
    for (int g = 0; g < GG; ++g)
        atomicMin(&sgmin[g], __float_as_uint(ming[g]));

    // t1 / ne: wave shuffle sum, then lane0 -> LDS atomic
#pragma unroll
    for (int off = 1; off < 64; off <<= 1) {
        t1 += __shfl_xor(t1, off);
        ne += __shfl_xor(ne, off);
    }
    if (lane == 0) { atomicAdd(&s_t1, t1); atomicAdd(&s_ne, ne); }
    __syncthreads();

    if (tid == 0) {
        atomicAdd(&ws[b],     s_t1);
        atomicAdd(&ws[4 + b], s_ne);
    }
    if (tid < GG) {
        unsigned* gm = reinterpret_cast<unsigned*>(ws) + 8;
        atomicMin(gm + b * GG + tid, sgmin[tid]);
    }
}

__global__ void ghd_final(const float* __restrict__ prob_y,
                          const float* __restrict__ ws,
                          float*       __restrict__ out) {
    // 256 threads: wave b handles batch b (tid = b*64 + g)
    const int tid = threadIdx.x;
    const int b = tid >> 6;
    const int g = tid & 63;
    const unsigned* gm = reinterpret_cast<const unsigned*>(ws) + 8;

    float mv  = __uint_as_float(gm[b * GG + g]);
    float py  = prob_y[b * GG + g];
    float pyf = (py > 0.2f) ? py : 0.0f;
#pragma unroll
    for (int off = 1; off < 64; off <<= 1) {
        mv  += __shfl_xor(mv, off);
        pyf += __shfl_xor(pyf, off);
    }
    __shared__ float res[4];
    if (g == 0) {
        float term1 = ws[b] / (ws[4 + b] + EPSV);
        float term2 = mv    / (pyf       + EPSV);
        res[b] = term1 + term2;
    }
    __syncthreads();
    if (tid == 0) out[0] = 0.25f * (res[0] + res[1] + res[2] + res[3]);
}

extern "C" void kernel_launch(void* const* d_in, const int* in_sizes, int n_in,
                              void* d_out, int out_size, void* d_ws, size_t ws_size,
                              hipStream_t stream) {
    const float* prob_map = (const float*)d_in[0];
    const float* prob_y   = (const float*)d_in[1];
    const float* gt       = (const float*)d_in[2];
    const int*   osz      = (const int*)d_in[3];
    float* out = (float*)d_out;
    float* ws  = (float*)d_ws;

    ghd_init<<<1, 256, 0, stream>>>(ws);
    dim3 grid(BLOCKS_X, BB);
    ghd_main<<<grid, 256, 0, stream>>>(prob_map, prob_y, gt, osz, ws);
    ghd_final<<<1, 256, 0, stream>>>(prob_y, ws, out);
}

// Round 3
// 88.661 us; speedup vs baseline: 4.5124x; 4.5124x over previous
//
#include <hip/hip_runtime.h>
#include <math.h>

#define HH 512
#define WW 512
#define PP (HH * WW)          // 262144 pixels
#define GG 64                 // gt points per batch
#define BB 4                  // batches
#define THREADS 256
#define NA 64                 // term-1 blocks per batch (16 pixels/thread)
#define NB 128                // term-2 blocks per batch (2 tiles/block)
#define TILE 1024
#define NTILES (PP / TILE)    // 256
#define MAX_DIST 724.0773439350246f   // sqrt(512^2 + 512^2)
#define EPSV 1e-6f

// Workspace layout (floats):
//   ws[0..3]    t1_sum[b]
//   ws[4..7]    n_est[b]
//   ws[8..263]  gmin bits, uint, [b][g]  (non-negative floats -> uint order-preserving)

__global__ void ghd_init(float* __restrict__ ws) {
    int t = threadIdx.x;
    if (t < 8) ws[t] = 0.0f;
    unsigned* gm = reinterpret_cast<unsigned*>(ws) + 8;
    if (t < BB * GG) gm[t] = 0x7f7fffffu;  // FLT_MAX bits
}

__launch_bounds__(THREADS)
__global__ void ghd_main(const float* __restrict__ prob_map,
                         const float* __restrict__ prob_y,
                         const float* __restrict__ gt,
                         const int*   __restrict__ osz,
                         float*       __restrict__ ws) {
    const int b    = blockIdx.y;
    const int tid  = threadIdx.x;
    const int lane = tid & 63;
    const int wave = tid >> 6;

    __shared__ float4   sdat[TILE];    // A: gdat[0..63]; B: pixel tile (nx0,nx1,p,base)
    __shared__ unsigned sgmin[GG];
    __shared__ float    s_t1[4], s_ne[4];

    const float nf0 = (float)osz[2 * b]     * (1.0f / HH);
    const float nf1 = (float)osz[2 * b + 1] * (1.0f / WW);
    const float* __restrict__ pm = prob_map + (size_t)b * PP;

    if (blockIdx.x < NA) {
        // ================= term 1 + n_est =================
        if (tid < GG) {
            float py = prob_y[b * GG + tid];
            sdat[tid] = make_float4(nf0 * gt[(b * GG + tid) * 2],
                                    nf1 * gt[(b * GG + tid) * 2 + 1],
                                    py, py * py);
        }
        __syncthreads();

        float t1 = 0.0f, ne = 0.0f;
        const float4* __restrict__ pm4 = (const float4*)pm;
#pragma unroll
        for (int c = 0; c < 4; ++c) {
            int   idx4 = (c * NA + blockIdx.x) * THREADS + tid;  // float4 index
            float4 p4  = pm4[idx4];
            int   pid  = idx4 * 4;
            float nx0  = nf0 * (float)(pid >> 9);
            float j0   = (float)(pid & (WW - 1));
            float nx1a = nf1 * j0;
            float nx1b = nf1 * (j0 + 1.0f);
            float nx1c = nf1 * (j0 + 2.0f);
            float nx1d = nf1 * (j0 + 3.0f);
            float ma = 3.4e38f, mb = 3.4e38f, mc = 3.4e38f, md = 3.4e38f;
#pragma unroll 16
            for (int g = 0; g < GG; ++g) {
                float4 gd  = sdat[g];
                float  dx  = nx0 - gd.x;
                float  dx2 = dx * dx;
                float  da = nx1a - gd.y, db = nx1b - gd.y;
                float  dc = nx1c - gd.y, dd = nx1d - gd.y;
                ma = fminf(ma, gd.w * fmaf(da, da, dx2));   // min_g (py^2 * d^2)
                mb = fminf(mb, gd.w * fmaf(db, db, dx2));
                mc = fminf(mc, gd.w * fmaf(dc, dc, dx2));
                md = fminf(md, gd.w * fmaf(dd, dd, dx2));
            }
            t1 += p4.x * __builtin_amdgcn_sqrtf(ma) + p4.y * __builtin_amdgcn_sqrtf(mb)
                + p4.z * __builtin_amdgcn_sqrtf(mc) + p4.w * __builtin_amdgcn_sqrtf(md);
            ne += p4.x + p4.y + p4.z + p4.w;
        }
#pragma unroll
        for (int off = 1; off < 64; off <<= 1) {
            t1 += __shfl_xor(t1, off);
            ne += __shfl_xor(ne, off);
        }
        if (lane == 0) { s_t1[wave] = t1; s_ne[wave] = ne; }
        __syncthreads();
        if (tid == 0) {
            atomicAdd(&ws[b],     s_t1[0] + s_t1[1] + s_t1[2] + s_t1[3]);
            atomicAdd(&ws[4 + b], s_ne[0] + s_ne[1] + s_ne[2] + s_ne[3]);
        }
    } else {
        // ================= term 2 =================
        // lane owns gt point g = lane (in registers); wave scans a quarter of each tile.
        if (tid < GG) sgmin[tid] = 0x7f7fffffu;
        const int g  = lane;
        const float gx = nf0 * gt[(b * GG + g) * 2];
        const float gy = nf1 * gt[(b * GG + g) * 2 + 1];
        const float py = prob_y[b * GG + g];
        float gmin = 3.4e38f;

        const int bx = blockIdx.x - NA;
        for (int t = bx; t < NTILES; t += NB) {     // exactly 2 tiles per block
            __syncthreads();
#pragma unroll
            for (int i = tid; i < TILE; i += THREADS) {
                int   pid = t * TILE + i;
                float p   = pm[pid];
                sdat[i] = make_float4(nf0 * (float)(pid >> 9),
                                      nf1 * (float)(pid & (WW - 1)),
                                      p,
                                      fmaf(-p, MAX_DIST, MAX_DIST));  // (1-p)*MAX
            }
            __syncthreads();
            const float4* __restrict__ mytile = sdat + wave * (TILE / 4);
#pragma unroll 8
            for (int k = 0; k < TILE / 4; ++k) {
                float4 px = mytile[k];               // broadcast: all lanes same addr
                float  dx = px.x - gx, dy = px.y - gy;
                float  d  = __builtin_amdgcn_sqrtf(fmaf(dx, dx, dy * dy));
                gmin = fminf(gmin, fmaf(px.z * py, d, px.w));  // p*py*d + (1-p)*MAX
            }
        }
        atomicMin(&sgmin[g], __float_as_uint(gmin));
        __syncthreads();
        if (tid < GG) {
            unsigned* gm = reinterpret_cast<unsigned*>(ws) + 8;
            atomicMin(gm + b * GG + tid, sgmin[tid]);
        }
    }
}

__global__ void ghd_final(const float* __restrict__ prob_y,
                          const float* __restrict__ ws,
                          float*       __restrict__ out) {
    // 256 threads: wave b handles batch b (tid = b*64 + g)
    const int tid = threadIdx.x;
    const int b = tid >> 6;
    const int g = tid & 63;
    const unsigned* gm = reinterpret_cast<const unsigned*>(ws) + 8;

    float mv  = __uint_as_float(gm[b * GG + g]);
    float py  = prob_y[b * GG + g];
    float pyf = (py > 0.2f) ? py : 0.0f;
#pragma unroll
    for (int off = 1; off < 64; off <<= 1) {
        mv  += __shfl_xor(mv, off);
        pyf += __shfl_xor(pyf, off);
    }
    __shared__ float res[4];
    if (g == 0) {
        float term1 = ws[b] / (ws[4 + b] + EPSV);
        float term2 = mv    / (pyf       + EPSV);
        res[b] = term1 + term2;
    }
    __syncthreads();
    if (tid == 0) out[0] = 0.25f * (res[0] + res[1] + res[2] + res[3]);
}

extern "C" void kernel_launch(void* const* d_in, const int* in_sizes, int n_in,
                              void* d_out, int out_size, void* d_ws, size_t ws_size,
                              hipStream_t stream) {
    const float* prob_map = (const float*)d_in[0];
    const float* prob_y   = (const float*)d_in[1];
    const float* gt       = (const float*)d_in[2];
    const int*   osz      = (const int*)d_in[3];
    float* out = (float*)d_out;
    float* ws  = (float*)d_ws;

    ghd_init<<<1, 256, 0, stream>>>(ws);
    dim3 grid(NA + NB, BB);
    ghd_main<<<grid, 256, 0, stream>>>(prob_map, prob_y, gt, osz, ws);
    ghd_final<<<1, 256, 0, stream>>>(prob_y, ws, out);
}